// Round 1
// 338.806 us; speedup vs baseline: 1.1437x; 1.1437x over previous
//
#include <hip/hip_runtime.h>
#include <stdint.h>

#define BS 4
#define NN 1024
#define GD 6
#define CIN 256
#define NH 8
#define DH 32
#define HID 16
#define MCS 64

#define PG_ELEMS (BS*NN*NN*GD)                 // 25165824
#define OUT_OFF  PG_ELEMS
#define MASK_OFF (PG_ELEMS + BS*NN*CIN)        // 26214400

typedef float vfloat4 __attribute__((ext_vector_type(4)));   // native clang vector
typedef unsigned vuint4 __attribute__((ext_vector_type(4)));

#if __has_builtin(__builtin_amdgcn_rcpf)
__device__ __forceinline__ float fast_rcp(float x) { return __builtin_amdgcn_rcpf(x); }
#else
__device__ __forceinline__ float fast_rcp(float x) { return 1.0f / x; }
#endif
#if __has_builtin(__builtin_amdgcn_exp2f)
__device__ __forceinline__ float fast_exp2(float x) { return __builtin_amdgcn_exp2f(x); }
#else
__device__ __forceinline__ float fast_exp2(float x) { return exp2f(x); }
#endif
#define LOG2E 1.44269504088896340736f

// swish via v_exp_f32 + v_rcp_f32 (5 instrs; avoids full IEEE divide sequence)
__device__ __forceinline__ float swishf(float x) {
    return x * fast_rcp(1.0f + fast_exp2(x * -LOG2E));
}

// Fused 4096x256 @ 256x256 + bias GEMM; blockIdx.y selects one of up to 3 (W,b,dst).
// Transposed LDS X-tile: inner loop = 1 broadcast ds_read_b128 + 1 float4 W load + 16 fma per k.
__global__ __launch_bounds__(256) void gemm3(const float* __restrict__ X,
    const float* __restrict__ W0, const float* __restrict__ B0, float* __restrict__ D0,
    const float* __restrict__ W1, const float* __restrict__ B1, float* __restrict__ D1,
    const float* __restrict__ W2, const float* __restrict__ B2, float* __restrict__ D2)
{
    const float* W; const float* Bv; float* D;
    if (blockIdx.y == 0)      { W = W0; Bv = B0; D = D0; }
    else if (blockIdx.y == 1) { W = W1; Bv = B1; D = D1; }
    else                      { W = W2; Bv = B2; D = D2; }
    const int tid = threadIdx.x;
    const int c4  = tid & 63;        // column quad: cols 4*c4 .. 4*c4+3
    const int rg  = tid >> 6;        // row group: rows r0+4*rg .. r0+4*rg+3
    const int r0  = blockIdx.x * 16;

    __shared__ float xsT[CIN][20];   // [k][row], padded 16->20 to spread write banks
    {
        float tmp[16];
        #pragma unroll
        for (int r = 0; r < 16; ++r) tmp[r] = X[(size_t)(r0 + r)*CIN + tid];
        vfloat4* dst = (vfloat4*)&xsT[tid][0];
        #pragma unroll
        for (int j = 0; j < 4; ++j)
            dst[j] = (vfloat4){tmp[4*j+0], tmp[4*j+1], tmp[4*j+2], tmp[4*j+3]};
    }
    __syncthreads();

    vfloat4 a0 = (vfloat4){0.f,0.f,0.f,0.f};
    vfloat4 a1 = a0, a2 = a0, a3 = a0;
    const vfloat4* W4 = (const vfloat4*)W;
    #pragma unroll 4
    for (int k = 0; k < CIN; ++k) {
        vfloat4 w  = W4[(size_t)k*64 + c4];                 // coalesced 1 KB/wave
        vfloat4 xr = *(const vfloat4*)&xsT[k][rg*4];        // wave-uniform broadcast b128
        a0 += xr.x * w;
        a1 += xr.y * w;
        a2 += xr.z * w;
        a3 += xr.w * w;
    }
    vfloat4 bb = ((const vfloat4*)Bv)[c4];
    vfloat4* D4 = (vfloat4*)D;
    const size_t rbase = (size_t)(r0 + rg*4);
    D4[(rbase+0)*64 + c4] = a0 + bb;
    D4[(rbase+1)*64 + c4] = a1 + bb;
    D4[(rbase+2)*64 + c4] = a2 + bb;
    D4[(rbase+3)*64 + c4] = a3 + bb;
}

// One block per (query i, batch b).
__global__ __launch_bounds__(256, 8) void attn_topk(
    const float* __restrict__ pg, const int* __restrict__ mask,
    const float* __restrict__ lW1g, const float* __restrict__ lb1g,
    const float* __restrict__ lW2g, const float* __restrict__ lb2g,
    const float* __restrict__ lW3g, const float* __restrict__ lb3g,
    const float* __restrict__ Q, const float* __restrict__ Kc, const float* __restrict__ Vc,
    float* __restrict__ O, float* __restrict__ pg_out, float* __restrict__ mask_out)
{
    const int i = blockIdx.x, b = blockIdx.y, tid = threadIdx.x;
    const int lane = tid & 63;

    // union: select phase -> hist[256] u32 @0, eqlist[64] u32 @256 ; later -> sc[64][8] f32
    __shared__ __align__(16) unsigned selbuf[512];   // 2 KB
    __shared__ float sg[MCS*7];                      // compact nbhd_g, stride 7
    __shared__ int nj[MCS];                          // bit31 = invalid flag
    __shared__ __align__(16) unsigned joff[MCS];     // float4 row offsets into Q/K/V space
    __shared__ vfloat4 obuf[4][64];                  // per-wave output partials (4 KB)
    __shared__ unsigned wsum[4];
    __shared__ unsigned sel_bin, sel_need, s_cnt, s_eqcnt;

    float (*sc)[NH]   = (float (*)[NH])selbuf;
    unsigned* hist    = selbuf;
    unsigned* eqlist  = selbuf + 256;

    const int* mrow = mask + b*NN;
    // mask passthrough folded in (formerly a separate kernel)
    if (tid == 0) mask_out[b*NN + i] = mrow[i] ? 1.0f : 0.0f;

    // ---- coalesced passthrough copy (nontemporal stores; pg_out never re-read) ----
    const size_t rowoff = (size_t)(b*NN + i) * (NN*GD);
    const vfloat4* src4 = (const vfloat4*)(pg + rowoff);
    vfloat4* dst4 = (vfloat4*)(pg_out + rowoff);
    #pragma unroll
    for (int t = 0; t < 6; ++t) {
        vfloat4 v = src4[tid + 256*t];
        __builtin_nontemporal_store(v, &dst4[tid + 256*t]);
    }
    // prefetch Q row quad (channels 4q..4q+3) for feat phase
    vfloat4 q4 = ((const vfloat4*)Q)[(size_t)(b*NN + i)*64 + (tid & 63)];

    // ---- per-thread rows j=4t..4t+3: 6 consecutive float4 (L2-warm), dist^2 in regs ----
    const int4 mv = ((const int4*)mrow)[tid];
    const vfloat4* gg = src4 + tid*6;
    vfloat4 g0 = gg[0], g1 = gg[1], g2 = gg[2], g3 = gg[3], g4 = gg[4], g5 = gg[5];
    float rv[4][6];
    rv[0][0]=g0.x; rv[0][1]=g0.y; rv[0][2]=g0.z; rv[0][3]=g0.w; rv[0][4]=g1.x; rv[0][5]=g1.y;
    rv[1][0]=g1.z; rv[1][1]=g1.w; rv[1][2]=g2.x; rv[1][3]=g2.y; rv[1][4]=g2.z; rv[1][5]=g2.w;
    rv[2][0]=g3.x; rv[2][1]=g3.y; rv[2][2]=g3.z; rv[2][3]=g3.w; rv[2][4]=g4.x; rv[2][5]=g4.y;
    rv[3][0]=g4.z; rv[3][1]=g4.w; rv[3][2]=g5.x; rv[3][3]=g5.y; rv[3][4]=g5.z; rv[3][5]=g5.w;
    const int vb[4] = { mv.x, mv.y, mv.z, mv.w };
    unsigned key[4];
    #pragma unroll
    for (int r = 0; r < 4; ++r) {
        float d2 = rv[r][0]*rv[r][0] + rv[r][1]*rv[r][1] + rv[r][2]*rv[r][2]
                 + rv[r][3]*rv[r][3] + rv[r][4]*rv[r][4] + rv[r][5]*rv[r][5];
        key[r] = __float_as_uint(vb[r] ? d2 : 1e30f);
    }

    // ---- 4-level radix select: find exact 64-smallest threshold ----
    unsigned prefix = 0;
    int need = MCS;
    for (int level = 0; level < 4; ++level) {
        const int shift = 24 - 8*level;
        hist[tid] = 0;
        __syncthreads();
        if (level == 0) {
            #pragma unroll
            for (int r = 0; r < 4; ++r) {
                unsigned d = key[r] >> 24;
                unsigned long long todo = __ballot(true);
                while (todo) {
                    int leader = (int)(__ffsll((unsigned long long)todo) - 1);
                    unsigned dl = __shfl(d, leader);
                    unsigned long long match = __ballot(d == dl);
                    if (lane == leader) atomicAdd(&hist[dl], (unsigned)__popcll(match));
                    todo &= ~match;
                }
            }
        } else {
            const unsigned pmask = 0xFFFFFFFFu << (shift + 8);
            #pragma unroll
            for (int r = 0; r < 4; ++r)
                if ((key[r] & pmask) == prefix)
                    atomicAdd(&hist[(key[r] >> shift) & 0xFFu], 1u);
        }
        __syncthreads();
        unsigned own = hist[tid];
        unsigned v = own;
        #pragma unroll
        for (int off = 1; off < 64; off <<= 1) {
            unsigned nv = __shfl_up(v, off);
            if (lane >= off) v += nv;
        }
        if (lane == 63) wsum[tid >> 6] = v;
        __syncthreads();
        unsigned basec = 0;
        for (int w = 0; w < (tid >> 6); ++w) basec += wsum[w];
        unsigned incl = v + basec;
        unsigned excl = incl - own;
        if (excl < (unsigned)need && (unsigned)need <= incl) {
            sel_bin = (unsigned)tid;
            sel_need = (unsigned)need - excl;
        }
        __syncthreads();
        prefix |= (sel_bin << shift);
        need = (int)sel_need;
    }
    const unsigned T = prefix;
    const int needT = need;

    if (tid == 0) { s_cnt = 0; s_eqcnt = 0; }
    __syncthreads();
    // ---- compaction: owners scatter their selected rows straight into LDS ----
    #pragma unroll
    for (int r = 0; r < 4; ++r) {
        unsigned kk = key[r];
        int j = tid*4 + r;
        if (kk < T) {
            unsigned p = atomicAdd(&s_cnt, 1u);
            nj[p] = j | (vb[r] ? 0 : (int)0x80000000);
            #pragma unroll
            for (int g = 0; g < GD; ++g) sg[p*7 + g] = rv[r][g];
        } else if (kk == T) {
            unsigned e = atomicAdd(&s_eqcnt, 1u);
            if (e < 64) eqlist[e] = (unsigned)j;
        }
    }
    __syncthreads();
    const int cbase = (int)s_cnt;
    if (tid == 0) {
        int ec = (int)s_eqcnt; if (ec > 64) ec = 64;
        for (int s2 = 0; s2 < needT; ++s2) {
            int bi = -1, bj = 0x7FFFFFFF;
            for (int e = 0; e < ec; ++e) {
                int jj = (int)eqlist[e];
                if (jj < bj) { bj = jj; bi = e; }
            }
            if (bi >= 0) {
                eqlist[bi] = 0x7FFFFFFFu;
                nj[cbase + s2] = bj | (mrow[bj] ? 0 : (int)0x80000000);
            }
        }
    }
    __syncthreads();
    // owners of tie keys fill the g-values for the tie slots (needT is tiny)
    #pragma unroll
    for (int r = 0; r < 4; ++r) {
        if (key[r] == T) {
            int j = tid*4 + r;
            for (int s2 = 0; s2 < needT; ++s2)
                if ((nj[cbase + s2] & 0x7FFFFFFF) == j) {
                    #pragma unroll
                    for (int g = 0; g < GD; ++g) sg[(cbase + s2)*7 + g] = rv[r][g];
                }
        }
    }
    __syncthreads();   // nj+sg ready; selbuf now reusable as sc[][]

    // precompute float4 row offsets (shared by feat + out phases)
    if (tid < MCS) joff[tid] = ((unsigned)(b*NN + (nj[tid] & 0x7FFFFFFF))) << 6;

    // ---- location-kernel MLP: wave-uniform head -> scalar (s_load) weights ----
    // invalid neighbors are baked to -1e38 here (removes per-m mask check in feat)
    #pragma unroll
    for (int pass = 0; pass < 2; ++pass) {
        const int h = __builtin_amdgcn_readfirstlane((tid >> 6) + pass*4);   // 0..7
        const int m = lane;
        const float* W1h = lW1g + h*(GD*HID);
        const float* B1h = lb1g + h*HID;
        const float* W2h = lW2g + h*(HID*HID);
        const float* B2h = lb2g + h*HID;
        const float* W3h = lW3g + h*HID;
        float gv[GD];
        #pragma unroll
        for (int g = 0; g < GD; ++g) gv[g] = sg[m*7 + g];
        float h1[HID];
        #pragma unroll
        for (int kk = 0; kk < HID; ++kk) {
            float a = B1h[kk];
            #pragma unroll
            for (int g = 0; g < GD; ++g) a += gv[g] * W1h[g*HID + kk];
            h1[kk] = swishf(a);
        }
        float h2[HID];
        #pragma unroll
        for (int l = 0; l < HID; ++l) {
            float a = B2h[l];
            #pragma unroll
            for (int kk = 0; kk < HID; ++kk) a += h1[kk] * W2h[kk*HID + l];
            h2[l] = swishf(a);
        }
        float a3 = lb3g[h];
        #pragma unroll
        for (int kk = 0; kk < HID; ++kk) a3 += h2[kk] * W3h[kk];
        sc[m][h] = (nj[m] < 0) ? -1e38f : swishf(a3);
    }
    __syncthreads();

    // ---- feat: wave p owns m = 16p..16p+15; lane q owns channel quad 4q..4q+3.
    //      Coalesced float4 K loads (1 KB/wave/m), dot4, 3-step 8-lane reduce. ----
    const int q = tid & 63;
    const int p = tid >> 6;
    const int hh = q >> 3;                 // head of this channel quad
    q4 *= 0.17677669529663688f;            // fold 1/sqrt(32) into q
    const vfloat4* Kc4 = (const vfloat4*)Kc;
    const vuint4* jo4 = (const vuint4*)(joff + (p << 4));
    #pragma unroll
    for (int mg = 0; mg < 4; ++mg) {
        vuint4 o4 = jo4[mg];
        #pragma unroll
        for (int r = 0; r < 4; ++r) {
            const int mm = (p << 4) + (mg << 2) + r;
            vfloat4 kv = Kc4[o4[r] + (unsigned)q];
            float d = q4.x * kv.x;
            d = fmaf(q4.y, kv.y, d);
            d = fmaf(q4.z, kv.z, d);
            d = fmaf(q4.w, kv.w, d);
            d += __shfl_xor(d, 1);
            d += __shfl_xor(d, 2);
            d += __shfl_xor(d, 4);
            if ((q & 7) == 0) sc[mm][hh] += d;   // one lane per (m,h); -1e38 stays -1e38
        }
    }
    __syncthreads();

    // ---- softmax over m, wave-parallel: lane = m, wave (x2 passes) = head ----
    #pragma unroll
    for (int pass = 0; pass < 2; ++pass) {
        int h = (tid >> 6) + pass*4;
        float s = sc[lane][h];
        float mx = s;
        #pragma unroll
        for (int off = 32; off; off >>= 1) mx = fmaxf(mx, __shfl_xor(mx, off));
        float e = fast_exp2((s - mx) * LOG2E);
        float sum = e;
        #pragma unroll
        for (int off = 32; off; off >>= 1) sum += __shfl_xor(sum, off);
        sc[lane][h] = e * fast_rcp(sum);
    }
    __syncthreads();

    // ---- out: same partition; coalesced float4 V loads; 4 wave-partials reduced in LDS ----
    {
        const vfloat4* Vc4 = (const vfloat4*)Vc;
        vfloat4 acc = (vfloat4){0.f,0.f,0.f,0.f};
        #pragma unroll
        for (int mg = 0; mg < 4; ++mg) {
            vuint4 o4 = jo4[mg];
            #pragma unroll
            for (int r = 0; r < 4; ++r) {
                const int mm = (p << 4) + (mg << 2) + r;
                float a = sc[mm][hh];
                vfloat4 v4 = Vc4[o4[r] + (unsigned)q];
                acc += a * v4;
            }
        }
        obuf[p][q] = acc;
    }
    __syncthreads();
    {
        const float* ob = (const float*)obuf;
        float s = ob[tid] + ob[256 + tid] + ob[512 + tid] + ob[768 + tid];
        O[(size_t)(b*NN + i)*CIN + tid] = s;
    }
}

extern "C" void kernel_launch(void* const* d_in, const int* in_sizes, int n_in,
                              void* d_out, int out_size, void* d_ws, size_t ws_size,
                              hipStream_t stream) {
    const float* pg   = (const float*)d_in[0];
    const float* x    = (const float*)d_in[1];
    const int*   mask = (const int*)d_in[2];
    const float* lW1  = (const float*)d_in[3];
    const float* lb1  = (const float*)d_in[4];
    const float* lW2  = (const float*)d_in[5];
    const float* lb2  = (const float*)d_in[6];
    const float* lW3  = (const float*)d_in[7];
    const float* lb3  = (const float*)d_in[8];
    const float* Wq   = (const float*)d_in[9];
    const float* bq   = (const float*)d_in[10];
    const float* Wk   = (const float*)d_in[11];
    const float* bk   = (const float*)d_in[12];
    const float* Wv   = (const float*)d_in[13];
    const float* bv   = (const float*)d_in[14];
    const float* Wo   = (const float*)d_in[15];
    const float* bo   = (const float*)d_in[16];

    float* out = (float*)d_out;
    float* Q  = (float*)d_ws;
    float* Kc = Q  + (size_t)BS*NN*CIN;
    float* Vc = Kc + (size_t)BS*NN*CIN;
    float* O  = Vc + (size_t)BS*NN*CIN;

    // QKV projections (z = 0,1,2)
    gemm3<<<dim3(BS*NN/16, 3), 256, 0, stream>>>(x, Wq, bq, Q, Wk, bk, Kc, Wv, bv, Vc);
    // top-k + attention (also performs the pairwise_g passthrough copy + mask write)
    attn_topk<<<dim3(NN, BS), 256, 0, stream>>>(pg, mask, lW1, lb1, lW2, lb2, lW3, lb3,
                                                Q, Kc, Vc, O, out, out + MASK_OFF);
    // output projection
    gemm3<<<dim3(BS*NN/16, 1), 256, 0, stream>>>(O, Wo, bo, out + OUT_OFF,
                                                 Wo, bo, out + OUT_OFF,
                                                 Wo, bo, out + OUT_OFF);
}